// Round 5
// baseline (221.571 us; speedup 1.0000x reference)
//
#include <hip/hip_runtime.h>
#include <math.h>

#define NROWS 8192
#define D     64
#define BHALF 1024              // antithetic fold: b and b+1024 merged
#define NSEG  8
#define BSEGN (BHALF / NSEG)    // 128 folded b per block
#define BT    64                // b per chunk
#define NCH   (BSEGN / BT)      // 2 chunks
#define ROWT  64                // rows per block (4 waves x 16-row strips)
#define NTILE (NROWS / ROWT)    // 128 row-tiles (one counter each)

typedef short bf16x8 __attribute__((ext_vector_type(8)));
typedef float f32x4  __attribute__((ext_vector_type(4)));

__device__ __forceinline__ unsigned short f2bf(float f) {
    unsigned int u = __float_as_uint(f);
    u = (u + 0x7FFFu + ((u >> 16) & 1u)) >> 16;   // round-to-nearest-even
    return (unsigned short)u;
}
__device__ __forceinline__ float bf2f(unsigned short h) {
    return __uint_as_float(((unsigned int)h) << 16);
}

// v_sin/v_cos take revolutions; v_fract does the range reduction.
__device__ __forceinline__ void fast_sincos(float x, float* sn, float* cs) {
    float rev = x * 0.15915494309189535f;
    rev = __builtin_amdgcn_fractf(rev);
    *sn = __builtin_amdgcn_sinf(rev);
    *cs = __builtin_amdgcn_cosf(rev);
}

// ---------------------------------------------------------------------------
// Precompute (fold b>=1024 into b<1024: sim'=-sim, mat'=-mat):
//   c[b][j] = eps[b][j]/lam[j]; split bf16 (ch + cl)
//   mat closed form, stored transposed bf16 matT[i][b] (B-frag-ready)
//   w2s[b] = w[b]+w[b+1024], w2c[b] = w[2048+b]-w[3072+b]
// Also zeroes the NTILE split-K counters (runs before main on same stream,
// re-cleared every call -> graph-replay safe under 0xAA ws poison).
// ---------------------------------------------------------------------------
__global__ void ssgp_precompute(const float* __restrict__ eps,
                                const float* __restrict__ lam,
                                const float* __restrict__ eta,
                                const float* __restrict__ w,
                                unsigned short* __restrict__ ch,
                                unsigned short* __restrict__ cl,
                                unsigned short* __restrict__ matT,
                                float* __restrict__ w2s,
                                float* __restrict__ w2c,
                                int* __restrict__ ctr) {
    int idx = blockIdx.x * 256 + threadIdx.x;      // b*64 + i, b < 1024
    int b = idx >> 6;
    int i = idx & 63;
    float e2 = eta[0] * eta[0];
    float c = eps[idx] / lam[i];
    unsigned short h = f2bf(c);
    ch[idx] = h;
    cl[idx] = f2bf(c - bf2f(h));
    float m;
    if (i < 32) m =  eps[b * D + i + 32] / lam[i + 32];
    else        m = -eps[b * D + i - 32] / lam[i - 32] - e2 * c;
    matT[i * BHALF + b] = f2bf(m);
    if (i == 0) {
        w2s[b] = w[b] + w[b + BHALF];
        w2c[b] = w[2048 + b] - w[3072 + b];
    }
    if (blockIdx.x == 0 && threadIdx.x < NTILE) ctr[threadIdx.x] = 0;
}

// ---------------------------------------------------------------------------
// Fused: sim tile = X*C^T (split-bf16 MFMA) -> sincos/scale -> wave-private
// LDS layout swap (C/D -> A-frag) -> F += G*matT (bf16 MFMA) -> partial
// store -> split-K last-arrival reduce (fence/atomic protocol per G16).
// Layouts (verified m89/m91/m120):
//   C/D:    col = lane&15, row = (lane>>4)*4 + reg
//   A/B-frag: [m|n = lane&15][k = (lane>>4)*8 + j], 8 contiguous bf16 in k
// ---------------------------------------------------------------------------
__global__ __launch_bounds__(256, 4) void ssgp_main(
        const float* __restrict__ x,
        const unsigned short* __restrict__ ch,
        const unsigned short* __restrict__ cl,
        const unsigned short* __restrict__ matT,
        const float* __restrict__ w2s,
        const float* __restrict__ w2c,
        float* __restrict__ partial,
        int* __restrict__ ctr,
        float* __restrict__ out) {
    __shared__ unsigned short g_lds[4][16][72];   // per-wave 16x64 g tile
    __shared__ int lastflag;
    const int t    = threadIdx.x;
    const int wv   = t >> 6;
    const int lane = t & 63;
    const int l15  = lane & 15;
    const int q    = lane >> 4;
    const int rbase = blockIdx.x * ROWT;
    const int row0 = rbase + wv * 16;               // this wave's row strip
    const int seg  = blockIdx.y;

    // x A-frags: row = row0+l15, k = kc*32 + q*8 + j; split hi/lo bf16
    bf16x8 xh[2], xl[2];
    {
        const float* xp = x + (size_t)(row0 + l15) * D + q * 8;
        #pragma unroll
        for (int kc = 0; kc < 2; ++kc) {
            #pragma unroll
            for (int e = 0; e < 8; ++e) {
                float f = xp[kc * 32 + e];
                unsigned short h = f2bf(f);
                xh[kc][e] = (short)h;
                xl[kc][e] = (short)f2bf(f - bf2f(h));
            }
        }
    }

    f32x4 facc[4];
    #pragma unroll
    for (int si = 0; si < 4; ++si) facc[si] = f32x4{0.f, 0.f, 0.f, 0.f};

    #pragma unroll
    for (int cbk = 0; cbk < NCH; ++cbk) {
        const int b0 = seg * BSEGN + cbk * BT;

        // ---- GEMM1 (split-bf16, 3 passes) + sincos + scale -> LDS
        #pragma unroll
        for (int st = 0; st < 4; ++st) {
            const int brow = b0 + st * 16 + l15;
            const unsigned short* cph = ch + (size_t)brow * D + q * 8;
            const unsigned short* cpl = cl + (size_t)brow * D + q * 8;
            f32x4 sim = f32x4{0.f, 0.f, 0.f, 0.f};
            #pragma unroll
            for (int kc = 0; kc < 2; ++kc) {
                bf16x8 bh = *(const bf16x8*)(cph + kc * 32);
                bf16x8 bl = *(const bf16x8*)(cpl + kc * 32);
                sim = __builtin_amdgcn_mfma_f32_16x16x32_bf16(xh[kc], bh, sim, 0, 0, 0);
                sim = __builtin_amdgcn_mfma_f32_16x16x32_bf16(xh[kc], bl, sim, 0, 0, 0);
                sim = __builtin_amdgcn_mfma_f32_16x16x32_bf16(xl[kc], bh, sim, 0, 0, 0);
            }
            const float ws = w2s[brow];
            const float wc = w2c[brow];
            #pragma unroll
            for (int r = 0; r < 4; ++r) {
                float sn, cs;
                fast_sincos(sim[r], &sn, &cs);
                float g = cs * wc - sn * ws;
                g_lds[wv][q * 4 + r][st * 16 + l15] = f2bf(g);
            }
        }
        // same-wave LDS RAW -> compiler inserts lgkmcnt wait; no barrier

        // ---- GEMM2: F(16x64) += G(16x64) * matT^T  (K = 64)
        #pragma unroll
        for (int kc2 = 0; kc2 < 2; ++kc2) {
            bf16x8 gf = *(const bf16x8*)&g_lds[wv][l15][kc2 * 32 + q * 8];
            #pragma unroll
            for (int si = 0; si < 4; ++si) {
                const unsigned short* mp =
                    matT + (size_t)(si * 16 + l15) * BHALF + b0 + kc2 * 32 + q * 8;
                bf16x8 mf = *(const bf16x8*)mp;
                facc[si] = __builtin_amdgcn_mfma_f32_16x16x32_bf16(gf, mf, facc[si], 0, 0, 0);
            }
        }
    }

    // ---- store partial plane: row = row0 + q*4 + r, col = si*16 + l15
    float* pp = partial + ((size_t)seg * NROWS + row0) * D;
    #pragma unroll
    for (int si = 0; si < 4; ++si) {
        #pragma unroll
        for (int r = 0; r < 4; ++r) {
            pp[(size_t)(q * 4 + r) * D + si * 16 + l15] = facc[si][r];
        }
    }

    // ---- split-K last-arrival reduce
    __threadfence();      // release: partial visible device-wide (L2 wb)
    __syncthreads();      // all threads of block past their fence
    if (t == 0) {
        int old = atomicAdd(&ctr[blockIdx.x], 1);   // device-scope (m20)
        if (old == NSEG - 1) __threadfence();       // acquire: inv L1/L2
        lastflag = (old == NSEG - 1);
    }
    __syncthreads();
    if (lastflag) {
        // sum NSEG planes for this 64-row tile: 1024 float4, 4 per thread
        const float4* p4 = (const float4*)partial;
        float4* o4 = (float4*)out;
        const size_t stride4 = (size_t)NROWS * D / 4;
        const size_t base4 = (size_t)rbase * D / 4;
        #pragma unroll
        for (int k = 0; k < 4; ++k) {
            size_t off = base4 + k * 256 + t;
            float4 a = p4[off];
            #pragma unroll
            for (int s = 1; s < NSEG; ++s) {
                float4 v = p4[off + s * stride4];
                a.x += v.x; a.y += v.y; a.z += v.z; a.w += v.w;
            }
            o4[off] = a;
        }
    }
}

extern "C" void kernel_launch(void* const* d_in, const int* in_sizes, int n_in,
                              void* d_out, int out_size, void* d_ws, size_t ws_size,
                              hipStream_t stream) {
    // setup_inputs order: t, x, epsilon, lam, eta, w
    const float* x   = (const float*)d_in[1];
    const float* eps = (const float*)d_in[2];
    const float* lam = (const float*)d_in[3];
    const float* eta = (const float*)d_in[4];
    const float* w   = (const float*)d_in[5];
    float* out = (float*)d_out;

    unsigned short* ch   = (unsigned short*)d_ws;          // 1024*64 ushort
    unsigned short* cl   = ch + BHALF * D;
    unsigned short* matT = cl + BHALF * D;
    float* w2s     = (float*)(matT + BHALF * D);           // 1024 f32
    float* w2c     = w2s + BHALF;
    float* partial = w2c + BHALF;                          // NSEG*8192*64 f32
    int*   ctr     = (int*)(partial + (size_t)NSEG * NROWS * D);  // NTILE ints

    ssgp_precompute<<<(BHALF * D) / 256, 256, 0, stream>>>(
        eps, lam, eta, w, ch, cl, matT, w2s, w2c, ctr);

    dim3 grid(NTILE, NSEG);
    ssgp_main<<<grid, 256, 0, stream>>>(x, ch, cl, matT, w2s, w2c,
                                        partial, ctr, out);
}

// Round 6
// 216.889 us; speedup vs baseline: 1.0216x; 1.0216x over previous
//
#include <hip/hip_runtime.h>
#include <math.h>

#define NROWS 8192
#define D     64
#define BHALF 1024              // antithetic fold: b and b+1024 merged
#define NSEG  8
#define BSEGN (BHALF / NSEG)    // 128 folded b per block
#define BT    64                // b per chunk
#define NCH   (BSEGN / BT)      // 2 chunks
#define ROWT  64                // rows per block (4 waves x 16-row strips)
#define NTILE (NROWS / ROWT)    // 128 row-tiles (one counter each)

typedef short bf16x8 __attribute__((ext_vector_type(8)));
typedef float f32x4  __attribute__((ext_vector_type(4)));

__device__ __forceinline__ unsigned short f2bf(float f) {
    unsigned int u = __float_as_uint(f);
    u = (u + 0x7FFFu + ((u >> 16) & 1u)) >> 16;   // round-to-nearest-even
    return (unsigned short)u;
}
__device__ __forceinline__ float bf2f(unsigned short h) {
    return __uint_as_float(((unsigned int)h) << 16);
}

// v_sin/v_cos take revolutions; v_fract does the range reduction.
__device__ __forceinline__ void fast_sincos(float x, float* sn, float* cs) {
    float rev = x * 0.15915494309189535f;
    rev = __builtin_amdgcn_fractf(rev);
    *sn = __builtin_amdgcn_sinf(rev);
    *cs = __builtin_amdgcn_cosf(rev);
}

// ---------------------------------------------------------------------------
// Precompute (fold b>=1024 into b<1024: sim'=-sim, mat'=-mat):
//   c[b][j] = eps[b][j]/lam[j]; split bf16 (ch + cl)
//   mat closed form, stored transposed bf16 matT[i][b] (B-frag-ready)
//   w2s[b] = w[b]+w[b+1024], w2c[b] = w[2048+b]-w[3072+b]
// Also zeroes the NTILE split-K counters (same stream -> ordered before main;
// re-cleared every call -> graph-replay safe under 0xAA ws poison).
// ---------------------------------------------------------------------------
__global__ void ssgp_precompute(const float* __restrict__ eps,
                                const float* __restrict__ lam,
                                const float* __restrict__ eta,
                                const float* __restrict__ w,
                                unsigned short* __restrict__ ch,
                                unsigned short* __restrict__ cl,
                                unsigned short* __restrict__ matT,
                                float* __restrict__ w2s,
                                float* __restrict__ w2c,
                                int* __restrict__ ctr) {
    int idx = blockIdx.x * 256 + threadIdx.x;      // b*64 + i, b < 1024
    int b = idx >> 6;
    int i = idx & 63;
    float e2 = eta[0] * eta[0];
    float c = eps[idx] / lam[i];
    unsigned short h = f2bf(c);
    ch[idx] = h;
    cl[idx] = f2bf(c - bf2f(h));
    float m;
    if (i < 32) m =  eps[b * D + i + 32] / lam[i + 32];
    else        m = -eps[b * D + i - 32] / lam[i - 32] - e2 * c;
    matT[i * BHALF + b] = f2bf(m);
    if (i == 0) {
        w2s[b] = w[b] + w[b + BHALF];
        w2c[b] = w[2048 + b] - w[3072 + b];
    }
    if (blockIdx.x == 0 && threadIdx.x < NTILE) ctr[threadIdx.x] = 0;
}

// ---------------------------------------------------------------------------
// Fused: sim tile = X*C^T (split-bf16 MFMA) -> sincos/scale -> wave-private
// LDS layout swap (C/D -> A-frag) -> F += G*matT (bf16 MFMA) -> partial
// store -> split-K last-arrival reduce (fence/atomic protocol per G16).
// NOTE: __launch_bounds__(256) ONLY — adding ",4" (R5) forced VGPR<=128 and
// the allocator spilled fragments to scratch (VGPR_Count 140->40, main
// 45->153 us). Do not re-add without checking -Rpass-analysis first.
// Layouts (verified m89/m91/m120):
//   C/D:    col = lane&15, row = (lane>>4)*4 + reg
//   A/B-frag: [m|n = lane&15][k = (lane>>4)*8 + j], 8 contiguous bf16 in k
// ---------------------------------------------------------------------------
__global__ __launch_bounds__(256) void ssgp_main(
        const float* __restrict__ x,
        const unsigned short* __restrict__ ch,
        const unsigned short* __restrict__ cl,
        const unsigned short* __restrict__ matT,
        const float* __restrict__ w2s,
        const float* __restrict__ w2c,
        float* __restrict__ partial,
        int* __restrict__ ctr,
        float* __restrict__ out) {
    __shared__ unsigned short g_lds[4][16][72];   // per-wave 16x64 g tile
    __shared__ int lastflag;
    const int t    = threadIdx.x;
    const int wv   = t >> 6;
    const int lane = t & 63;
    const int l15  = lane & 15;
    const int q    = lane >> 4;
    const int rbase = blockIdx.x * ROWT;
    const int row0 = rbase + wv * 16;               // this wave's row strip
    const int seg  = blockIdx.y;

    // x A-frags: row = row0+l15, k = kc*32 + q*8 + j; split hi/lo bf16
    bf16x8 xh[2], xl[2];
    {
        const float* xp = x + (size_t)(row0 + l15) * D + q * 8;
        #pragma unroll
        for (int kc = 0; kc < 2; ++kc) {
            #pragma unroll
            for (int e = 0; e < 8; ++e) {
                float f = xp[kc * 32 + e];
                unsigned short h = f2bf(f);
                xh[kc][e] = (short)h;
                xl[kc][e] = (short)f2bf(f - bf2f(h));
            }
        }
    }

    f32x4 facc[4];
    #pragma unroll
    for (int si = 0; si < 4; ++si) facc[si] = f32x4{0.f, 0.f, 0.f, 0.f};

    #pragma unroll
    for (int cbk = 0; cbk < NCH; ++cbk) {
        const int b0 = seg * BSEGN + cbk * BT;

        // ---- GEMM1 (split-bf16, 3 passes) + sincos + scale -> LDS
        #pragma unroll
        for (int st = 0; st < 4; ++st) {
            const int brow = b0 + st * 16 + l15;
            const unsigned short* cph = ch + (size_t)brow * D + q * 8;
            const unsigned short* cpl = cl + (size_t)brow * D + q * 8;
            f32x4 sim = f32x4{0.f, 0.f, 0.f, 0.f};
            #pragma unroll
            for (int kc = 0; kc < 2; ++kc) {
                bf16x8 bh = *(const bf16x8*)(cph + kc * 32);
                bf16x8 bl = *(const bf16x8*)(cpl + kc * 32);
                sim = __builtin_amdgcn_mfma_f32_16x16x32_bf16(xh[kc], bh, sim, 0, 0, 0);
                sim = __builtin_amdgcn_mfma_f32_16x16x32_bf16(xh[kc], bl, sim, 0, 0, 0);
                sim = __builtin_amdgcn_mfma_f32_16x16x32_bf16(xl[kc], bh, sim, 0, 0, 0);
            }
            const float ws = w2s[brow];
            const float wc = w2c[brow];
            #pragma unroll
            for (int r = 0; r < 4; ++r) {
                float sn, cs;
                fast_sincos(sim[r], &sn, &cs);
                float g = cs * wc - sn * ws;
                g_lds[wv][q * 4 + r][st * 16 + l15] = f2bf(g);
            }
        }
        // same-wave LDS RAW -> compiler inserts lgkmcnt wait; no barrier

        // ---- GEMM2: F(16x64) += G(16x64) * matT^T  (K = 64)
        #pragma unroll
        for (int kc2 = 0; kc2 < 2; ++kc2) {
            bf16x8 gf = *(const bf16x8*)&g_lds[wv][l15][kc2 * 32 + q * 8];
            #pragma unroll
            for (int si = 0; si < 4; ++si) {
                const unsigned short* mp =
                    matT + (size_t)(si * 16 + l15) * BHALF + b0 + kc2 * 32 + q * 8;
                bf16x8 mf = *(const bf16x8*)mp;
                facc[si] = __builtin_amdgcn_mfma_f32_16x16x32_bf16(gf, mf, facc[si], 0, 0, 0);
            }
        }
    }

    // ---- store partial plane: row = row0 + q*4 + r, col = si*16 + l15
    float* pp = partial + ((size_t)seg * NROWS + row0) * D;
    #pragma unroll
    for (int si = 0; si < 4; ++si) {
        #pragma unroll
        for (int r = 0; r < 4; ++r) {
            pp[(size_t)(q * 4 + r) * D + si * 16 + l15] = facc[si][r];
        }
    }

    // ---- split-K last-arrival reduce
    __threadfence();      // release: partial visible device-wide (L2 wb)
    __syncthreads();      // all threads of block past their fence
    if (t == 0) {
        int old = atomicAdd(&ctr[blockIdx.x], 1);   // device-scope (m20)
        if (old == NSEG - 1) __threadfence();       // acquire: inv L1/L2
        lastflag = (old == NSEG - 1);
    }
    __syncthreads();
    if (lastflag) {
        // sum NSEG planes for this 64-row tile: 1024 float4, 4 per thread
        const float4* p4 = (const float4*)partial;
        float4* o4 = (float4*)out;
        const size_t stride4 = (size_t)NROWS * D / 4;
        const size_t base4 = (size_t)rbase * D / 4;
        #pragma unroll
        for (int k = 0; k < 4; ++k) {
            size_t off = base4 + k * 256 + t;
            float4 a = p4[off];
            #pragma unroll
            for (int s = 1; s < NSEG; ++s) {
                float4 v = p4[off + s * stride4];
                a.x += v.x; a.y += v.y; a.z += v.z; a.w += v.w;
            }
            o4[off] = a;
        }
    }
}

extern "C" void kernel_launch(void* const* d_in, const int* in_sizes, int n_in,
                              void* d_out, int out_size, void* d_ws, size_t ws_size,
                              hipStream_t stream) {
    // setup_inputs order: t, x, epsilon, lam, eta, w
    const float* x   = (const float*)d_in[1];
    const float* eps = (const float*)d_in[2];
    const float* lam = (const float*)d_in[3];
    const float* eta = (const float*)d_in[4];
    const float* w   = (const float*)d_in[5];
    float* out = (float*)d_out;

    unsigned short* ch   = (unsigned short*)d_ws;          // 1024*64 ushort
    unsigned short* cl   = ch + BHALF * D;
    unsigned short* matT = cl + BHALF * D;
    float* w2s     = (float*)(matT + BHALF * D);           // 1024 f32
    float* w2c     = w2s + BHALF;
    float* partial = w2c + BHALF;                          // NSEG*8192*64 f32
    int*   ctr     = (int*)(partial + (size_t)NSEG * NROWS * D);  // NTILE ints

    ssgp_precompute<<<(BHALF * D) / 256, 256, 0, stream>>>(
        eps, lam, eta, w, ch, cl, matT, w2s, w2c, ctr);

    dim3 grid(NTILE, NSEG);
    ssgp_main<<<grid, 256, 0, stream>>>(x, ch, cl, matT, w2s, w2c,
                                        partial, ctr, out);
}

// Round 8
// 90.940 us; speedup vs baseline: 2.4364x; 2.3850x over previous
//
#include <hip/hip_runtime.h>
#include <math.h>

#define NROWS 8192
#define D     64
#define BHALF 1024              // antithetic fold: b and b+1024 merged
#define ROWT  16                // rows per block (all 8 waves share them)
#define NTILE (NROWS / ROWT)    // 512 blocks
#define WPB   8                 // waves per block
#define BPW   (BHALF / WPB)     // 128 folded b per wave
#define BT    64                // b per chunk
#define NCH   (BPW / BT)        // 2 chunks per wave

// g region (phase 1): 8 waves x 16 rows x 72 ushort = 18432 B
#define GSTRIDE  72
#define GPLANE   (16 * GSTRIDE)         // ushorts per wave plane (1152)
// reduce region (phase 2, overlays g after sync): 8 planes x 16 x 66 f32
// = 33792 B. stride 66 -> only free 2-way bank overlap (m136).
#define RSTRIDE  66
#define RPLANE   (16 * RSTRIDE)         // floats per plane (1056)
// R7 BUG: was WPB*GPLANE*2 = 18432 B; reduce planes p>=5 ran out of bounds.
// Size for the LARGER phase:
#define SMEM_BYTES (WPB * RPLANE * 4)   // 33792 B

typedef short bf16x8 __attribute__((ext_vector_type(8)));
typedef float f32x4  __attribute__((ext_vector_type(4)));

__device__ __forceinline__ unsigned short f2bf(float f) {
    unsigned int u = __float_as_uint(f);
    u = (u + 0x7FFFu + ((u >> 16) & 1u)) >> 16;   // round-to-nearest-even
    return (unsigned short)u;
}
__device__ __forceinline__ float bf2f(unsigned short h) {
    return __uint_as_float(((unsigned int)h) << 16);
}

// v_sin/v_cos take revolutions; v_fract does the range reduction.
__device__ __forceinline__ void fast_sincos(float x, float* sn, float* cs) {
    float rev = x * 0.15915494309189535f;
    rev = __builtin_amdgcn_fractf(rev);
    *sn = __builtin_amdgcn_sinf(rev);
    *cs = __builtin_amdgcn_cosf(rev);
}

// ---------------------------------------------------------------------------
// Precompute (fold b>=1024 into b<1024: sim'=-sim, mat'=-mat):
//   c[b][j] = eps[b][j]/lam[j]; split bf16 (ch + cl)
//   mat closed form, stored transposed bf16 matT[i][b] (B-frag-ready)
//   w2s[b] = w[b]+w[b+1024], w2c[b] = w[2048+b]-w[3072+b]
// ---------------------------------------------------------------------------
__global__ void ssgp_precompute(const float* __restrict__ eps,
                                const float* __restrict__ lam,
                                const float* __restrict__ eta,
                                const float* __restrict__ w,
                                unsigned short* __restrict__ ch,
                                unsigned short* __restrict__ cl,
                                unsigned short* __restrict__ matT,
                                float* __restrict__ w2s,
                                float* __restrict__ w2c) {
    int idx = blockIdx.x * 256 + threadIdx.x;      // b*64 + i, b < 1024
    int b = idx >> 6;
    int i = idx & 63;
    float e2 = eta[0] * eta[0];
    float c = eps[idx] / lam[i];
    unsigned short h = f2bf(c);
    ch[idx] = h;
    cl[idx] = f2bf(c - bf2f(h));
    float m;
    if (i < 32) m =  eps[b * D + i + 32] / lam[i + 32];
    else        m = -eps[b * D + i - 32] / lam[i - 32] - e2 * c;
    matT[i * BHALF + b] = f2bf(m);
    if (i == 0) {
        w2s[b] = w[b] + w[b + BHALF];
        w2c[b] = w[2048 + b] - w[3072 + b];
    }
}

// ---------------------------------------------------------------------------
// Fused, block-complete: each block owns 16 output rows entirely.
// 8 waves x disjoint 128-b slices; per wave: sim = X*C^T (split-bf16 MFMA)
// -> sincos/scale -> wave-private LDS g tile (C/D -> A-frag swap) ->
// F += G*matT (bf16 MFMA). Then LDS block-reduce of the 8 facc tiles ->
// direct out store. No partial buffer, no atomics, no fences, no 2nd kernel.
// (R5/R6 lesson: per-block __threadfence() split-K reduce cost ~110 us of
//  serialized L2-writeback — never again at this granularity.)
// Layouts (verified m89/m91/m120):
//   C/D:      col = lane&15, row = (lane>>4)*4 + reg
//   A/B-frag: [m|n = lane&15][k = (lane>>4)*8 + j], 8 contiguous bf16 in k
// ---------------------------------------------------------------------------
__global__ __launch_bounds__(512) void ssgp_main(
        const float* __restrict__ x,
        const unsigned short* __restrict__ ch,
        const unsigned short* __restrict__ cl,
        const unsigned short* __restrict__ matT,
        const float* __restrict__ w2s,
        const float* __restrict__ w2c,
        float* __restrict__ out) {
    __shared__ __align__(16) unsigned char smem[SMEM_BYTES];
    unsigned short* g_lds = (unsigned short*)smem;   // phase 1 (18432 B used)
    float*          red   = (float*)smem;            // phase 2 (33792 B used)

    const int t    = threadIdx.x;
    const int wv   = t >> 6;            // 0..7
    const int lane = t & 63;
    const int l15  = lane & 15;
    const int q    = lane >> 4;
    const int rbase = blockIdx.x * ROWT;

    // x A-frags: row = rbase+l15 (same 16 rows for all waves; L1-resident),
    // k = kc*32 + q*8 + j; split hi/lo bf16
    bf16x8 xh[2], xl[2];
    {
        const float* xp = x + (size_t)(rbase + l15) * D + q * 8;
        #pragma unroll
        for (int kc = 0; kc < 2; ++kc) {
            #pragma unroll
            for (int e = 0; e < 8; ++e) {
                float f = xp[kc * 32 + e];
                unsigned short h = f2bf(f);
                xh[kc][e] = (short)h;
                xl[kc][e] = (short)f2bf(f - bf2f(h));
            }
        }
    }

    f32x4 facc[4];
    #pragma unroll
    for (int si = 0; si < 4; ++si) facc[si] = f32x4{0.f, 0.f, 0.f, 0.f};

    unsigned short* gw = g_lds + wv * GPLANE;   // this wave's private g tile

    #pragma unroll
    for (int cbk = 0; cbk < NCH; ++cbk) {
        const int b0 = wv * BPW + cbk * BT;

        // ---- GEMM1 (split-bf16, 3 passes) + sincos + scale -> LDS
        #pragma unroll
        for (int st = 0; st < 4; ++st) {
            const int brow = b0 + st * 16 + l15;
            const unsigned short* cph = ch + (size_t)brow * D + q * 8;
            const unsigned short* cpl = cl + (size_t)brow * D + q * 8;
            f32x4 sim = f32x4{0.f, 0.f, 0.f, 0.f};
            #pragma unroll
            for (int kc = 0; kc < 2; ++kc) {
                bf16x8 bh = *(const bf16x8*)(cph + kc * 32);
                bf16x8 bl = *(const bf16x8*)(cpl + kc * 32);
                sim = __builtin_amdgcn_mfma_f32_16x16x32_bf16(xh[kc], bh, sim, 0, 0, 0);
                sim = __builtin_amdgcn_mfma_f32_16x16x32_bf16(xh[kc], bl, sim, 0, 0, 0);
                sim = __builtin_amdgcn_mfma_f32_16x16x32_bf16(xl[kc], bh, sim, 0, 0, 0);
            }
            const float ws = w2s[brow];
            const float wc = w2c[brow];
            #pragma unroll
            for (int r = 0; r < 4; ++r) {
                float sn, cs;
                fast_sincos(sim[r], &sn, &cs);
                float g = cs * wc - sn * ws;
                gw[(q * 4 + r) * GSTRIDE + st * 16 + l15] = f2bf(g);
            }
        }
        // same-wave LDS RAW -> compiler inserts lgkmcnt wait; no barrier

        // ---- GEMM2: F(16x64) += G(16x64) * matT^T  (K = 64)
        #pragma unroll
        for (int kc2 = 0; kc2 < 2; ++kc2) {
            bf16x8 gf = *(const bf16x8*)(gw + l15 * GSTRIDE + kc2 * 32 + q * 8);
            #pragma unroll
            for (int si = 0; si < 4; ++si) {
                const unsigned short* mp =
                    matT + (size_t)(si * 16 + l15) * BHALF + b0 + kc2 * 32 + q * 8;
                bf16x8 mf = *(const bf16x8*)mp;
                facc[si] = __builtin_amdgcn_mfma_f32_16x16x32_bf16(gf, mf, facc[si], 0, 0, 0);
            }
        }
    }

    // ---- block reduce of the 8 wave tiles (LDS, overlaying g region)
    __syncthreads();    // all waves done reading their g tiles
    {
        float* rp = red + wv * RPLANE;
        #pragma unroll
        for (int si = 0; si < 4; ++si) {
            #pragma unroll
            for (int r = 0; r < 4; ++r) {
                rp[(q * 4 + r) * RSTRIDE + si * 16 + l15] = facc[si][r];
            }
        }
    }
    __syncthreads();
    {
        // 512 threads, 1024 outputs -> 2 consecutive f32 each
        const int row = t >> 5;          // (2t)>>6
        const int col = (2 * t) & 63;
        float sx = 0.f, sy = 0.f;
        #pragma unroll
        for (int p = 0; p < WPB; ++p) {
            const float* rp = red + p * RPLANE + row * RSTRIDE + col;
            sx += rp[0];
            sy += rp[1];
        }
        float2 v; v.x = sx; v.y = sy;
        *(float2*)(out + (size_t)(rbase + row) * D + col) = v;
    }
}

extern "C" void kernel_launch(void* const* d_in, const int* in_sizes, int n_in,
                              void* d_out, int out_size, void* d_ws, size_t ws_size,
                              hipStream_t stream) {
    // setup_inputs order: t, x, epsilon, lam, eta, w
    const float* x   = (const float*)d_in[1];
    const float* eps = (const float*)d_in[2];
    const float* lam = (const float*)d_in[3];
    const float* eta = (const float*)d_in[4];
    const float* w   = (const float*)d_in[5];
    float* out = (float*)d_out;

    unsigned short* ch   = (unsigned short*)d_ws;          // 1024*64 ushort
    unsigned short* cl   = ch + BHALF * D;
    unsigned short* matT = cl + BHALF * D;
    float* w2s = (float*)(matT + BHALF * D);               // 1024 f32
    float* w2c = w2s + BHALF;

    ssgp_precompute<<<(BHALF * D) / 256, 256, 0, stream>>>(
        eps, lam, eta, w, ch, cl, matT, w2s, w2c);

    ssgp_main<<<NTILE, 512, 0, stream>>>(x, ch, cl, matT, w2s, w2c, out);
}

// Round 9
// 90.580 us; speedup vs baseline: 2.4461x; 1.0040x over previous
//
#include <hip/hip_runtime.h>
#include <math.h>

#define NROWS 8192
#define D     64
#define BHALF 1024              // antithetic fold: b and b+1024 merged
#define ROWT  16                // rows per block (all 8 waves share them)
#define NTILE (NROWS / ROWT)    // 512 blocks
#define WPB   8                 // waves per block
#define BPW   (BHALF / WPB)     // 128 folded b per wave (ONE chunk, no loop)
#define NSTRIP (BPW / 16)       // 8 GEMM1 strips per wave

// g region (phase 1): 8 waves x 16 rows x 136 ushort (272 B rows, 16B-align)
#define GSTRIDE  136
#define GPLANE   (16 * GSTRIDE)         // ushorts per wave plane (2176)
// reduce region (phase 2, overlays g after sync): 8 planes x 16 x 66 f32
#define RSTRIDE  66
#define RPLANE   (16 * RSTRIDE)         // floats per plane (1056)
// size for the LARGER phase: g = 8*2176*2 = 34816 B > reduce 33792 B
#define SMEM_BYTES (WPB * GPLANE * 2)

typedef short bf16x8 __attribute__((ext_vector_type(8)));
typedef float f32x4  __attribute__((ext_vector_type(4)));

__device__ __forceinline__ unsigned short f2bf(float f) {
    unsigned int u = __float_as_uint(f);
    u = (u + 0x7FFFu + ((u >> 16) & 1u)) >> 16;   // round-to-nearest-even
    return (unsigned short)u;
}
__device__ __forceinline__ float bf2f(unsigned short h) {
    return __uint_as_float(((unsigned int)h) << 16);
}

// v_sin/v_cos take revolutions; v_fract does the range reduction.
__device__ __forceinline__ void fast_sincos(float x, float* sn, float* cs) {
    float rev = x * 0.15915494309189535f;
    rev = __builtin_amdgcn_fractf(rev);
    *sn = __builtin_amdgcn_sinf(rev);
    *cs = __builtin_amdgcn_cosf(rev);
}

// ---------------------------------------------------------------------------
// Precompute (fold b>=1024 into b<1024: sim'=-sim, mat'=-mat):
//   c[b][j] = eps[b][j]/lam[j]; split bf16 (ch + cl)
//   mat closed form, stored transposed bf16 matT[i][b] (B-frag-ready)
//   w2s[b] = w[b]+w[b+1024], w2c[b] = w[2048+b]-w[3072+b]
// ---------------------------------------------------------------------------
__global__ void ssgp_precompute(const float* __restrict__ eps,
                                const float* __restrict__ lam,
                                const float* __restrict__ eta,
                                const float* __restrict__ w,
                                unsigned short* __restrict__ ch,
                                unsigned short* __restrict__ cl,
                                unsigned short* __restrict__ matT,
                                float* __restrict__ w2s,
                                float* __restrict__ w2c) {
    int idx = blockIdx.x * 256 + threadIdx.x;      // b*64 + i, b < 1024
    int b = idx >> 6;
    int i = idx & 63;
    float e2 = eta[0] * eta[0];
    float c = eps[idx] / lam[i];
    unsigned short h = f2bf(c);
    ch[idx] = h;
    cl[idx] = f2bf(c - bf2f(h));
    float m;
    if (i < 32) m =  eps[b * D + i + 32] / lam[i + 32];
    else        m = -eps[b * D + i - 32] / lam[i - 32] - e2 * c;
    matT[i * BHALF + b] = f2bf(m);
    if (i == 0) {
        w2s[b] = w[b] + w[b + BHALF];
        w2c[b] = w[2048 + b] - w[3072 + b];
    }
}

// ---------------------------------------------------------------------------
// Fused, block-complete: each block owns 16 output rows entirely.
// 8 waves x disjoint 128-b slices, processed as ONE chunk per wave:
//   8 independent GEMM1 strips (split-bf16 MFMA) -> sincos/scale -> LDS g
//   tile (C/D -> A-frag swap) -> single K=128 GEMM2 -> LDS block reduce ->
//   direct out store. No partials/atomics/fences (R5/R6: fence split-K cost
//   ~110 us). Single chunk removes the R8 LDS WAR serialization between
//   chunk GEMM2 reads and next-chunk GEMM1 writes.
// Layouts (verified m89/m91/m120):
//   C/D:      col = lane&15, row = (lane>>4)*4 + reg
//   A/B-frag: [m|n = lane&15][k = (lane>>4)*8 + j], 8 contiguous bf16 in k
// ---------------------------------------------------------------------------
__global__ __launch_bounds__(512) void ssgp_main(
        const float* __restrict__ x,
        const unsigned short* __restrict__ ch,
        const unsigned short* __restrict__ cl,
        const unsigned short* __restrict__ matT,
        const float* __restrict__ w2s,
        const float* __restrict__ w2c,
        float* __restrict__ out) {
    __shared__ __align__(16) unsigned char smem[SMEM_BYTES];
    unsigned short* g_lds = (unsigned short*)smem;   // phase 1 (34816 B)
    float*          red   = (float*)smem;            // phase 2 (33792 B)

    const int t    = threadIdx.x;
    const int wv   = t >> 6;            // 0..7
    const int lane = t & 63;
    const int l15  = lane & 15;
    const int q    = lane >> 4;
    const int rbase = blockIdx.x * ROWT;

    // x A-frags: row = rbase+l15 (same 16 rows for all waves; L1-resident),
    // k = kc*32 + q*8 + j; split hi/lo bf16
    bf16x8 xh[2], xl[2];
    {
        const float* xp = x + (size_t)(rbase + l15) * D + q * 8;
        #pragma unroll
        for (int kc = 0; kc < 2; ++kc) {
            #pragma unroll
            for (int e = 0; e < 8; ++e) {
                float f = xp[kc * 32 + e];
                unsigned short h = f2bf(f);
                xh[kc][e] = (short)h;
                xl[kc][e] = (short)f2bf(f - bf2f(h));
            }
        }
    }

    f32x4 facc[4];
    #pragma unroll
    for (int si = 0; si < 4; ++si) facc[si] = f32x4{0.f, 0.f, 0.f, 0.f};

    unsigned short* gw = g_lds + wv * GPLANE;   // this wave's private g tile
    const int b0 = wv * BPW;

    // ---- GEMM1 (split-bf16, 3 passes) + sincos + scale -> LDS, 8 strips
    #pragma unroll
    for (int st = 0; st < NSTRIP; ++st) {
        const int brow = b0 + st * 16 + l15;
        const unsigned short* cph = ch + (size_t)brow * D + q * 8;
        const unsigned short* cpl = cl + (size_t)brow * D + q * 8;
        f32x4 sim = f32x4{0.f, 0.f, 0.f, 0.f};
        #pragma unroll
        for (int kc = 0; kc < 2; ++kc) {
            bf16x8 bh = *(const bf16x8*)(cph + kc * 32);
            bf16x8 bl = *(const bf16x8*)(cpl + kc * 32);
            sim = __builtin_amdgcn_mfma_f32_16x16x32_bf16(xh[kc], bh, sim, 0, 0, 0);
            sim = __builtin_amdgcn_mfma_f32_16x16x32_bf16(xh[kc], bl, sim, 0, 0, 0);
            sim = __builtin_amdgcn_mfma_f32_16x16x32_bf16(xl[kc], bh, sim, 0, 0, 0);
        }
        const float ws = w2s[brow];
        const float wc = w2c[brow];
        #pragma unroll
        for (int r = 0; r < 4; ++r) {
            float sn, cs;
            fast_sincos(sim[r], &sn, &cs);
            float g = cs * wc - sn * ws;
            gw[(q * 4 + r) * GSTRIDE + st * 16 + l15] = f2bf(g);
        }
    }
    // same-wave LDS RAW -> compiler inserts lgkmcnt wait; no barrier

    // ---- GEMM2: F(16x64) += G(16x128) * matT^T  (K = 128, single pass)
    #pragma unroll
    for (int kc2 = 0; kc2 < 4; ++kc2) {
        bf16x8 gf = *(const bf16x8*)(gw + l15 * GSTRIDE + kc2 * 32 + q * 8);
        #pragma unroll
        for (int si = 0; si < 4; ++si) {
            const unsigned short* mp =
                matT + (size_t)(si * 16 + l15) * BHALF + b0 + kc2 * 32 + q * 8;
            bf16x8 mf = *(const bf16x8*)mp;
            facc[si] = __builtin_amdgcn_mfma_f32_16x16x32_bf16(gf, mf, facc[si], 0, 0, 0);
        }
    }

    // ---- block reduce of the 8 wave tiles (LDS, overlaying g region)
    __syncthreads();    // all waves done reading their g tiles
    {
        float* rp = red + wv * RPLANE;
        #pragma unroll
        for (int si = 0; si < 4; ++si) {
            #pragma unroll
            for (int r = 0; r < 4; ++r) {
                rp[(q * 4 + r) * RSTRIDE + si * 16 + l15] = facc[si][r];
            }
        }
    }
    __syncthreads();
    {
        // 512 threads, 1024 outputs -> 2 consecutive f32 each
        const int row = t >> 5;          // (2t)>>6
        const int col = (2 * t) & 63;
        float sx = 0.f, sy = 0.f;
        #pragma unroll
        for (int p = 0; p < WPB; ++p) {
            const float* rp = red + p * RPLANE + row * RSTRIDE + col;
            sx += rp[0];
            sy += rp[1];
        }
        float2 v; v.x = sx; v.y = sy;
        *(float2*)(out + (size_t)(rbase + row) * D + col) = v;
    }
}

extern "C" void kernel_launch(void* const* d_in, const int* in_sizes, int n_in,
                              void* d_out, int out_size, void* d_ws, size_t ws_size,
                              hipStream_t stream) {
    // setup_inputs order: t, x, epsilon, lam, eta, w
    const float* x   = (const float*)d_in[1];
    const float* eps = (const float*)d_in[2];
    const float* lam = (const float*)d_in[3];
    const float* eta = (const float*)d_in[4];
    const float* w   = (const float*)d_in[5];
    float* out = (float*)d_out;

    unsigned short* ch   = (unsigned short*)d_ws;          // 1024*64 ushort
    unsigned short* cl   = ch + BHALF * D;
    unsigned short* matT = cl + BHALF * D;
    float* w2s = (float*)(matT + BHALF * D);               // 1024 f32
    float* w2c = w2s + BHALF;

    ssgp_precompute<<<(BHALF * D) / 256, 256, 0, stream>>>(
        eps, lam, eta, w, ch, cl, matT, w2s, w2c);

    ssgp_main<<<NTILE, 512, 0, stream>>>(x, ch, cl, matT, w2s, w2c, out);
}

// Round 10
// 80.326 us; speedup vs baseline: 2.7584x; 1.1277x over previous
//
#include <hip/hip_runtime.h>
#include <math.h>

#define NROWS 8192
#define D     64
#define BHALF 1024              // antithetic fold: b and b+1024 merged
#define ROWT  32                // rows per block (2 strips of 16, all waves)
#define NTILE (NROWS / ROWT)    // 256 blocks (1/CU)
#define WPB   8                 // waves per block
#define BPW   (BHALF / WPB)     // 128 folded b per wave
#define NSTRIP (BPW / 16)       // 8 GEMM1 b-strips per wave

// g region (phase 1): 8 waves x 2 row-strips x 16 rows x 136 ushort
#define GSTRIDE  136
#define GPLANE   (16 * GSTRIDE)             // ushorts per strip plane (2176)
#define SMEM_BYTES (WPB * 2 * GPLANE * 2)   // 69632 B
// reduce region (phase 2, overlays g): 8 planes x 32 rows x 66 f32 = 67584 B
#define RSTRIDE  66
#define RPLANE   (32 * RSTRIDE)

typedef short bf16x8 __attribute__((ext_vector_type(8)));
typedef float f32x4  __attribute__((ext_vector_type(4)));

__device__ __forceinline__ unsigned short f2bf(float f) {
    unsigned int u = __float_as_uint(f);
    u = (u + 0x7FFFu + ((u >> 16) & 1u)) >> 16;   // round-to-nearest-even
    return (unsigned short)u;
}
__device__ __forceinline__ float bf2f(unsigned short h) {
    return __uint_as_float(((unsigned int)h) << 16);
}

// v_sin/v_cos take revolutions; v_fract does the range reduction.
__device__ __forceinline__ void fast_sincos(float x, float* sn, float* cs) {
    float rev = x * 0.15915494309189535f;
    rev = __builtin_amdgcn_fractf(rev);
    *sn = __builtin_amdgcn_sinf(rev);
    *cs = __builtin_amdgcn_cosf(rev);
}

// ---------------------------------------------------------------------------
// Precompute (fold b>=1024 into b<1024: sim'=-sim, mat'=-mat):
//   c[b][j] = eps[b][j]/lam[j]; split bf16 (ch + cl)
//   mat closed form, stored transposed bf16 matT[i][b] (B-frag-ready)
//   w2s[b] = w[b]+w[b+1024], w2c[b] = w[2048+b]-w[3072+b]
// ---------------------------------------------------------------------------
__global__ void ssgp_precompute(const float* __restrict__ eps,
                                const float* __restrict__ lam,
                                const float* __restrict__ eta,
                                const float* __restrict__ w,
                                unsigned short* __restrict__ ch,
                                unsigned short* __restrict__ cl,
                                unsigned short* __restrict__ matT,
                                float* __restrict__ w2s,
                                float* __restrict__ w2c) {
    int idx = blockIdx.x * 256 + threadIdx.x;      // b*64 + i, b < 1024
    int b = idx >> 6;
    int i = idx & 63;
    float e2 = eta[0] * eta[0];
    float c = eps[idx] / lam[i];
    unsigned short h = f2bf(c);
    ch[idx] = h;
    cl[idx] = f2bf(c - bf2f(h));
    float m;
    if (i < 32) m =  eps[b * D + i + 32] / lam[i + 32];
    else        m = -eps[b * D + i - 32] / lam[i - 32] - e2 * c;
    matT[i * BHALF + b] = f2bf(m);
    if (i == 0) {
        w2s[b] = w[b] + w[b + BHALF];
        w2c[b] = w[2048 + b] - w[3072 + b];
    }
}

// ---------------------------------------------------------------------------
// Fused, block-complete, 32-row tiles: each wave applies its 128-b slice to
// TWO 16-row strips, so every bh/bl/mf fragment load feeds 2x the MFMAs and
// block-count halves (512->256) -> coefficient L2 traffic halves (~197->98MB).
// Flow per wave: 8 b-strips [load bh/bl once -> sim MFMAs for both row
// strips] -> sincos/scale -> 2 LDS g planes (C/D -> A-frag swap) -> GEMM2
// K=128 with mf shared across both strips -> LDS block reduce -> out.
// No partials/atomics/fences (R5/R6 lesson: fence split-K cost ~110 us).
// Layouts (verified m89/m91/m120):
//   C/D:      col = lane&15, row = (lane>>4)*4 + reg
//   A/B-frag: [m|n = lane&15][k = (lane>>4)*8 + j], 8 contiguous bf16 in k
// ---------------------------------------------------------------------------
__global__ __launch_bounds__(512) void ssgp_main(
        const float* __restrict__ x,
        const unsigned short* __restrict__ ch,
        const unsigned short* __restrict__ cl,
        const unsigned short* __restrict__ matT,
        const float* __restrict__ w2s,
        const float* __restrict__ w2c,
        float* __restrict__ out) {
    __shared__ __align__(16) unsigned char smem[SMEM_BYTES];
    unsigned short* g_lds = (unsigned short*)smem;   // phase 1 (69632 B)
    float*          red   = (float*)smem;            // phase 2 (67584 B)

    const int t    = threadIdx.x;
    const int wv   = t >> 6;            // 0..7
    const int lane = t & 63;
    const int l15  = lane & 15;
    const int q    = lane >> 4;
    const int rbase = blockIdx.x * ROWT;

    // x A-frags for both row strips: row = rbase + s*16 + l15,
    // k = kc*32 + q*8 + j; split hi/lo bf16
    bf16x8 xh[2][2], xl[2][2];          // [strip][kc]
    #pragma unroll
    for (int s = 0; s < 2; ++s) {
        const float* xp = x + (size_t)(rbase + s * 16 + l15) * D + q * 8;
        #pragma unroll
        for (int kc = 0; kc < 2; ++kc) {
            #pragma unroll
            for (int e = 0; e < 8; ++e) {
                float f = xp[kc * 32 + e];
                unsigned short h = f2bf(f);
                xh[s][kc][e] = (short)h;
                xl[s][kc][e] = (short)f2bf(f - bf2f(h));
            }
        }
    }

    f32x4 facc[2][4];
    #pragma unroll
    for (int s = 0; s < 2; ++s)
        #pragma unroll
        for (int si = 0; si < 4; ++si) facc[s][si] = f32x4{0.f, 0.f, 0.f, 0.f};

    unsigned short* gw = g_lds + wv * (2 * GPLANE);  // wave's 2 g planes
    const int b0 = wv * BPW;

    // ---- GEMM1: 8 b-strips; bh/bl loaded once, used by both row strips
    #pragma unroll
    for (int st = 0; st < NSTRIP; ++st) {
        const int brow = b0 + st * 16 + l15;
        const unsigned short* cph = ch + (size_t)brow * D + q * 8;
        const unsigned short* cpl = cl + (size_t)brow * D + q * 8;
        f32x4 sim0 = f32x4{0.f, 0.f, 0.f, 0.f};
        f32x4 sim1 = f32x4{0.f, 0.f, 0.f, 0.f};
        #pragma unroll
        for (int kc = 0; kc < 2; ++kc) {
            bf16x8 bh = *(const bf16x8*)(cph + kc * 32);
            bf16x8 bl = *(const bf16x8*)(cpl + kc * 32);
            sim0 = __builtin_amdgcn_mfma_f32_16x16x32_bf16(xh[0][kc], bh, sim0, 0, 0, 0);
            sim0 = __builtin_amdgcn_mfma_f32_16x16x32_bf16(xh[0][kc], bl, sim0, 0, 0, 0);
            sim0 = __builtin_amdgcn_mfma_f32_16x16x32_bf16(xl[0][kc], bh, sim0, 0, 0, 0);
            sim1 = __builtin_amdgcn_mfma_f32_16x16x32_bf16(xh[1][kc], bh, sim1, 0, 0, 0);
            sim1 = __builtin_amdgcn_mfma_f32_16x16x32_bf16(xh[1][kc], bl, sim1, 0, 0, 0);
            sim1 = __builtin_amdgcn_mfma_f32_16x16x32_bf16(xl[1][kc], bh, sim1, 0, 0, 0);
        }
        const float ws = w2s[brow];
        const float wc = w2c[brow];
        #pragma unroll
        for (int r = 0; r < 4; ++r) {
            float sn, cs;
            fast_sincos(sim0[r], &sn, &cs);
            gw[(q * 4 + r) * GSTRIDE + st * 16 + l15] = f2bf(cs * wc - sn * ws);
            fast_sincos(sim1[r], &sn, &cs);
            gw[GPLANE + (q * 4 + r) * GSTRIDE + st * 16 + l15] = f2bf(cs * wc - sn * ws);
        }
    }
    // same-wave LDS RAW -> compiler inserts lgkmcnt wait; no barrier

    // ---- GEMM2: F_s(16x64) += G_s(16x128) * matT^T; mf shared across s
    #pragma unroll
    for (int kc2 = 0; kc2 < 4; ++kc2) {
        bf16x8 gf0 = *(const bf16x8*)(gw + l15 * GSTRIDE + kc2 * 32 + q * 8);
        bf16x8 gf1 = *(const bf16x8*)(gw + GPLANE + l15 * GSTRIDE + kc2 * 32 + q * 8);
        #pragma unroll
        for (int si = 0; si < 4; ++si) {
            const unsigned short* mp =
                matT + (size_t)(si * 16 + l15) * BHALF + b0 + kc2 * 32 + q * 8;
            bf16x8 mf = *(const bf16x8*)mp;
            facc[0][si] = __builtin_amdgcn_mfma_f32_16x16x32_bf16(gf0, mf, facc[0][si], 0, 0, 0);
            facc[1][si] = __builtin_amdgcn_mfma_f32_16x16x32_bf16(gf1, mf, facc[1][si], 0, 0, 0);
        }
    }

    // ---- block reduce of the 8 wave tiles (LDS, overlaying g region)
    __syncthreads();    // all waves done reading their g tiles
    {
        float* rp = red + wv * RPLANE;
        #pragma unroll
        for (int s = 0; s < 2; ++s)
            #pragma unroll
            for (int si = 0; si < 4; ++si)
                #pragma unroll
                for (int r = 0; r < 4; ++r)
                    rp[(s * 16 + q * 4 + r) * RSTRIDE + si * 16 + l15] =
                        facc[s][si][r];
    }
    __syncthreads();
    {
        // 2048 outputs, 512 threads -> one float4 each
        const int row = t >> 4;          // 0..31
        const int col = (t & 15) * 4;    // 0..60
        float4 a; a.x = a.y = a.z = a.w = 0.f;
        #pragma unroll
        for (int p = 0; p < WPB; ++p) {
            const float* rp = red + p * RPLANE + row * RSTRIDE + col;
            a.x += rp[0]; a.y += rp[1]; a.z += rp[2]; a.w += rp[3];
        }
        *(float4*)(out + (size_t)(rbase + row) * D + col) = a;
    }
}

extern "C" void kernel_launch(void* const* d_in, const int* in_sizes, int n_in,
                              void* d_out, int out_size, void* d_ws, size_t ws_size,
                              hipStream_t stream) {
    // setup_inputs order: t, x, epsilon, lam, eta, w
    const float* x   = (const float*)d_in[1];
    const float* eps = (const float*)d_in[2];
    const float* lam = (const float*)d_in[3];
    const float* eta = (const float*)d_in[4];
    const float* w   = (const float*)d_in[5];
    float* out = (float*)d_out;

    unsigned short* ch   = (unsigned short*)d_ws;          // 1024*64 ushort
    unsigned short* cl   = ch + BHALF * D;
    unsigned short* matT = cl + BHALF * D;
    float* w2s = (float*)(matT + BHALF * D);               // 1024 f32
    float* w2c = w2s + BHALF;

    ssgp_precompute<<<(BHALF * D) / 256, 256, 0, stream>>>(
        eps, lam, eta, w, ch, cl, matT, w2s, w2c);

    ssgp_main<<<NTILE, 512, 0, stream>>>(x, ch, cl, matT, w2s, w2c, out);
}

// Round 11
// 77.280 us; speedup vs baseline: 2.8671x; 1.0394x over previous
//
#include <hip/hip_runtime.h>
#include <math.h>

#define NROWS 8192
#define D     64
#define BHALF 1024              // antithetic fold: b and b+1024 merged
#define ROWT  32                // rows per block (2 strips of 16, all waves)
#define NTILE (NROWS / ROWT)    // 256 blocks (1/CU)
#define WPB   8                 // waves per block
#define BPW   (BHALF / WPB)     // 128 folded b per wave
#define NSTRIP (BPW / 16)       // 8 GEMM1 b-strips per wave

// g region (phase 1): 8 waves x 2 row-strips x 16 rows x 136 ushort
#define GSTRIDE  136
#define GPLANE   (16 * GSTRIDE)             // ushorts per strip plane (2176)
#define SMEM_BYTES (WPB * 2 * GPLANE * 2)   // 69632 B
// reduce region (phase 2, overlays g): 8 planes x 32 rows x 66 f32 = 67584 B
#define RSTRIDE  66
#define RPLANE   (32 * RSTRIDE)

typedef short bf16x8 __attribute__((ext_vector_type(8)));
typedef float f32x4  __attribute__((ext_vector_type(4)));

__device__ __forceinline__ unsigned short f2bf(float f) {
    unsigned int u = __float_as_uint(f);
    u = (u + 0x7FFFu + ((u >> 16) & 1u)) >> 16;   // round-to-nearest-even
    return (unsigned short)u;
}
__device__ __forceinline__ float bf2f(unsigned short h) {
    return __uint_as_float(((unsigned int)h) << 16);
}

// v_sin/v_cos take revolutions; v_fract does the range reduction.
__device__ __forceinline__ void fast_sincos(float x, float* sn, float* cs) {
    float rev = x * 0.15915494309189535f;
    rev = __builtin_amdgcn_fractf(rev);
    *sn = __builtin_amdgcn_sinf(rev);
    *cs = __builtin_amdgcn_cosf(rev);
}

// ---------------------------------------------------------------------------
// Precompute (fold b>=1024 into b<1024: sim'=-sim, mat'=-mat):
//   ch[b][j] = bf16(eps[b][j]/lam[j])   (single bf16 — R11 drops the cl
//     low word: sim = (xh+xl)*bh keeps x at ~f32 precision, c at bf16;
//     adds ~0.016 rad sim error -> ~0.01 f error, inside the 0.064 budget)
//   mat closed form, stored TRANSPOSED bf16 matT[i][b] (B-frag-ready)
//   w2s[b] = w[b]+w[b+1024], w2c[b] = w[2048+b]-w[3072+b]
// ---------------------------------------------------------------------------
__global__ void ssgp_precompute(const float* __restrict__ eps,
                                const float* __restrict__ lam,
                                const float* __restrict__ eta,
                                const float* __restrict__ w,
                                unsigned short* __restrict__ ch,
                                unsigned short* __restrict__ matT,
                                float* __restrict__ w2s,
                                float* __restrict__ w2c) {
    int idx = blockIdx.x * 256 + threadIdx.x;      // b*64 + i, b < 1024
    int b = idx >> 6;
    int i = idx & 63;
    float e2 = eta[0] * eta[0];
    float c = eps[idx] / lam[i];
    ch[idx] = f2bf(c);
    float m;
    if (i < 32) m =  eps[b * D + i + 32] / lam[i + 32];
    else        m = -eps[b * D + i - 32] / lam[i - 32] - e2 * c;
    matT[i * BHALF + b] = f2bf(m);
    if (i == 0) {
        w2s[b] = w[b] + w[b + BHALF];
        w2c[b] = w[2048 + b] - w[3072 + b];
    }
}

// ---------------------------------------------------------------------------
// Fused, block-complete, 32-row tiles: each wave applies its 128-b slice to
// TWO 16-row strips (every bh/mf fragment load feeds 2x the MFMAs — the
// R10 lever that bought 90.6->80.3). R11: 2-pass split GEMM1 (xh+xl)*bh —
// one coefficient stream instead of two, 8 MFMAs/strip instead of 12.
// Flow per wave: 8 b-strips [load bh once -> 4 sim MFMAs x 2 row strips]
// -> sincos/scale -> 2 LDS g planes (C/D -> A-frag swap) -> GEMM2 K=128
// (mf shared across strips) -> LDS block reduce -> direct out store.
// No partials/atomics/fences (R5/R6: fence split-K cost ~110 us).
// Layouts (verified m89/m91/m120):
//   C/D:      col = lane&15, row = (lane>>4)*4 + reg
//   A/B-frag: [m|n = lane&15][k = (lane>>4)*8 + j], 8 contiguous bf16 in k
// ---------------------------------------------------------------------------
__global__ __launch_bounds__(512) void ssgp_main(
        const float* __restrict__ x,
        const unsigned short* __restrict__ ch,
        const unsigned short* __restrict__ matT,
        const float* __restrict__ w2s,
        const float* __restrict__ w2c,
        float* __restrict__ out) {
    __shared__ __align__(16) unsigned char smem[SMEM_BYTES];
    unsigned short* g_lds = (unsigned short*)smem;   // phase 1 (69632 B)
    float*          red   = (float*)smem;            // phase 2 (67584 B)

    const int t    = threadIdx.x;
    const int wv   = t >> 6;            // 0..7
    const int lane = t & 63;
    const int l15  = lane & 15;
    const int q    = lane >> 4;
    const int rbase = blockIdx.x * ROWT;

    // x A-frags for both row strips: row = rbase + s*16 + l15,
    // k = kc*32 + q*8 + j; split hi/lo bf16 (x stays ~f32-accurate)
    bf16x8 xh[2][2], xl[2][2];          // [strip][kc]
    #pragma unroll
    for (int s = 0; s < 2; ++s) {
        const float* xp = x + (size_t)(rbase + s * 16 + l15) * D + q * 8;
        #pragma unroll
        for (int kc = 0; kc < 2; ++kc) {
            #pragma unroll
            for (int e = 0; e < 8; ++e) {
                float f = xp[kc * 32 + e];
                unsigned short h = f2bf(f);
                xh[s][kc][e] = (short)h;
                xl[s][kc][e] = (short)f2bf(f - bf2f(h));
            }
        }
    }

    f32x4 facc[2][4];
    #pragma unroll
    for (int s = 0; s < 2; ++s)
        #pragma unroll
        for (int si = 0; si < 4; ++si) facc[s][si] = f32x4{0.f, 0.f, 0.f, 0.f};

    unsigned short* gw = g_lds + wv * (2 * GPLANE);  // wave's 2 g planes
    const int b0 = wv * BPW;

    // ---- GEMM1: 8 b-strips; bh loaded once, used by both row strips
    #pragma unroll
    for (int st = 0; st < NSTRIP; ++st) {
        const int brow = b0 + st * 16 + l15;
        const unsigned short* cph = ch + (size_t)brow * D + q * 8;
        f32x4 sim0 = f32x4{0.f, 0.f, 0.f, 0.f};
        f32x4 sim1 = f32x4{0.f, 0.f, 0.f, 0.f};
        #pragma unroll
        for (int kc = 0; kc < 2; ++kc) {
            bf16x8 bh = *(const bf16x8*)(cph + kc * 32);
            sim0 = __builtin_amdgcn_mfma_f32_16x16x32_bf16(xh[0][kc], bh, sim0, 0, 0, 0);
            sim0 = __builtin_amdgcn_mfma_f32_16x16x32_bf16(xl[0][kc], bh, sim0, 0, 0, 0);
            sim1 = __builtin_amdgcn_mfma_f32_16x16x32_bf16(xh[1][kc], bh, sim1, 0, 0, 0);
            sim1 = __builtin_amdgcn_mfma_f32_16x16x32_bf16(xl[1][kc], bh, sim1, 0, 0, 0);
        }
        const float ws = w2s[brow];
        const float wc = w2c[brow];
        #pragma unroll
        for (int r = 0; r < 4; ++r) {
            float sn, cs;
            fast_sincos(sim0[r], &sn, &cs);
            gw[(q * 4 + r) * GSTRIDE + st * 16 + l15] = f2bf(cs * wc - sn * ws);
            fast_sincos(sim1[r], &sn, &cs);
            gw[GPLANE + (q * 4 + r) * GSTRIDE + st * 16 + l15] = f2bf(cs * wc - sn * ws);
        }
    }
    // same-wave LDS RAW -> compiler inserts lgkmcnt wait; no barrier

    // ---- GEMM2: F_s(16x64) += G_s(16x128) * matT^T; mf shared across s
    #pragma unroll
    for (int kc2 = 0; kc2 < 4; ++kc2) {
        bf16x8 gf0 = *(const bf16x8*)(gw + l15 * GSTRIDE + kc2 * 32 + q * 8);
        bf16x8 gf1 = *(const bf16x8*)(gw + GPLANE + l15 * GSTRIDE + kc2 * 32 + q * 8);
        #pragma unroll
        for (int si = 0; si < 4; ++si) {
            const unsigned short* mp =
                matT + (size_t)(si * 16 + l15) * BHALF + b0 + kc2 * 32 + q * 8;
            bf16x8 mf = *(const bf16x8*)mp;
            facc[0][si] = __builtin_amdgcn_mfma_f32_16x16x32_bf16(gf0, mf, facc[0][si], 0, 0, 0);
            facc[1][si] = __builtin_amdgcn_mfma_f32_16x16x32_bf16(gf1, mf, facc[1][si], 0, 0, 0);
        }
    }

    // ---- block reduce of the 8 wave tiles (LDS, overlaying g region)
    __syncthreads();    // all waves done reading their g tiles
    {
        float* rp = red + wv * RPLANE;
        #pragma unroll
        for (int s = 0; s < 2; ++s)
            #pragma unroll
            for (int si = 0; si < 4; ++si)
                #pragma unroll
                for (int r = 0; r < 4; ++r)
                    rp[(s * 16 + q * 4 + r) * RSTRIDE + si * 16 + l15] =
                        facc[s][si][r];
    }
    __syncthreads();
    {
        // 2048 outputs, 512 threads -> one float4 each
        const int row = t >> 4;          // 0..31
        const int col = (t & 15) * 4;    // 0..60
        float4 a; a.x = a.y = a.z = a.w = 0.f;
        #pragma unroll
        for (int p = 0; p < WPB; ++p) {
            const float* rp = red + p * RPLANE + row * RSTRIDE + col;
            a.x += rp[0]; a.y += rp[1]; a.z += rp[2]; a.w += rp[3];
        }
        *(float4*)(out + (size_t)(rbase + row) * D + col) = a;
    }
}

extern "C" void kernel_launch(void* const* d_in, const int* in_sizes, int n_in,
                              void* d_out, int out_size, void* d_ws, size_t ws_size,
                              hipStream_t stream) {
    // setup_inputs order: t, x, epsilon, lam, eta, w
    const float* x   = (const float*)d_in[1];
    const float* eps = (const float*)d_in[2];
    const float* lam = (const float*)d_in[3];
    const float* eta = (const float*)d_in[4];
    const float* w   = (const float*)d_in[5];
    float* out = (float*)d_out;

    unsigned short* ch   = (unsigned short*)d_ws;          // 1024*64 ushort
    unsigned short* matT = ch + BHALF * D;                 // 1024*64 ushort
    float* w2s = (float*)(matT + BHALF * D);               // 1024 f32
    float* w2c = w2s + BHALF;

    ssgp_precompute<<<(BHALF * D) / 256, 256, 0, stream>>>(
        eps, lam, eta, w, ch, matT, w2s, w2c);

    ssgp_main<<<NTILE, 512, 0, stream>>>(x, ch, matT, w2s, w2c, out);
}